// Round 2
// baseline (1240.039 us; speedup 1.0000x reference)
//
#include <hip/hip_runtime.h>

typedef unsigned short u16;
typedef unsigned int   u32;
typedef __bf16 bf16x8 __attribute__((ext_vector_type(8)));
typedef float  f32x4  __attribute__((ext_vector_type(4)));
typedef u32    u32x4  __attribute__((ext_vector_type(4)));
typedef u16    u16x4  __attribute__((ext_vector_type(4)));

#define D_MODEL 1024
#define T_SEQ   2048
#define NH      16
#define HD      64

__device__ __forceinline__ float b2f(u16 u){ return __uint_as_float(((u32)u)<<16); }
__device__ __forceinline__ u16 f2b(float f){
  u32 x = __float_as_uint(f);
  x += 0x7fffu + ((x>>16)&1u);
  return (u16)(x>>16);
}

// ---------------- f32 -> bf16 elementwise convert (X) ----------------
__global__ __launch_bounds__(256) void f32_to_bf16(const float* __restrict__ src, u16* __restrict__ dst)
{
  const int i = (blockIdx.x*256 + threadIdx.x)<<2;
  f32x4 v = *(const f32x4*)(src + i);
  u16x4 o;
  o[0]=f2b(v[0]); o[1]=f2b(v[1]); o[2]=f2b(v[2]); o[3]=f2b(v[3]);
  *(u16x4*)(dst + i) = o;
}

// ---------------- weight transpose+convert: WT[n][k] = bf16(W[k][n]) ----------------
__global__ void transpose_w(const float* __restrict__ W0, const float* __restrict__ W1,
                            const float* __restrict__ W2, const float* __restrict__ W3,
                            u16* __restrict__ T0, u16* __restrict__ T1,
                            u16* __restrict__ T2, u16* __restrict__ T3)
{
  __shared__ u16 s[32][33];
  const int z = blockIdx.z;
  const float* src = (z==0)?W0:(z==1)?W1:(z==2)?W2:W3;
  u16*         dst = (z==0)?T0:(z==1)?T1:(z==2)?T2:T3;
  const int x = threadIdx.x, y = threadIdx.y;
  const int r0 = blockIdx.y*32, c0 = blockIdx.x*32;
  #pragma unroll
  for (int r=0;r<4;r++) s[y + r*8][x] = f2b(src[(r0 + y + r*8)*D_MODEL + c0 + x]);
  __syncthreads();
  #pragma unroll
  for (int r=0;r<4;r++) dst[(c0 + y + r*8)*D_MODEL + r0 + x] = s[x][y + r*8];
}

// ---------------- 128x128 MFMA GEMM:  C[4096][1024] = A[4096][1024] * Bt^T ----------
// A, Bt bf16 (Bt is N x K row-major). z selects weight/output.
// If outF non-null: f32 output; else bf16 to oB.
__global__ __launch_bounds__(256) void gemm128(
    const u16* __restrict__ A,
    const u16* __restrict__ B0, const u16* __restrict__ B1, const u16* __restrict__ B2,
    float* __restrict__ oF0, float* __restrict__ oF1, u16* __restrict__ oB)
{
  __shared__ __align__(16) u16 sA[128*40];
  __shared__ __align__(16) u16 sB[128*40];
  const int z = blockIdx.z;
  const u16* Bt   = (z==0)?B0:(z==1)?B1:B2;
  float*     outF = (z==0)?oF0:(z==1)?oF1:nullptr;

  const int tid = threadIdx.x;
  const int bm0 = blockIdx.y<<7, bn0 = blockIdx.x<<7;
  const int lane = tid & 63;
  const int wm = ((tid>>7)&1)<<6;   // wave row (0/64)
  const int wn = ((tid>>6)&1)<<6;   // wave col (0/64)
  const int q8 = (lane>>4)<<3;      // quad*8 (k offset in fragment)
  const int lr = lane & 15;

  const f32x4 z4 = {0.f,0.f,0.f,0.f};
  f32x4 acc[4][4];
  #pragma unroll
  for (int i=0;i<4;i++)
    #pragma unroll
    for (int j=0;j<4;j++) acc[i][j] = z4;

  for (int kt=0; kt<D_MODEL; kt+=32){
    #pragma unroll
    for (int i=0;i<2;i++){
      int c = tid + (i<<8);               // 512 chunks of 8 bf16
      int row = c>>2, col8 = (c&3)<<3;
      *(u32x4*)(sA + row*40 + col8) = *(const u32x4*)(A  + (bm0+row)*D_MODEL + kt + col8);
      *(u32x4*)(sB + row*40 + col8) = *(const u32x4*)(Bt + (bn0+row)*D_MODEL + kt + col8);
    }
    __syncthreads();
    bf16x8 af[4], bfr[4];
    #pragma unroll
    for (int i=0;i<4;i++) af[i]  = *(const bf16x8*)(sA + (wm + (i<<4) + lr)*40 + q8);
    #pragma unroll
    for (int j=0;j<4;j++) bfr[j] = *(const bf16x8*)(sB + (wn + (j<<4) + lr)*40 + q8);
    #pragma unroll
    for (int i=0;i<4;i++)
      #pragma unroll
      for (int j=0;j<4;j++)
        acc[i][j] = __builtin_amdgcn_mfma_f32_16x16x32_bf16(af[i], bfr[j], acc[i][j], 0, 0, 0);
    __syncthreads();
  }

  const int rq = (lane>>4)<<2;
  #pragma unroll
  for (int i=0;i<4;i++){
    #pragma unroll
    for (int r=0;r<4;r++){
      int grow = bm0 + wm + (i<<4) + rq + r;
      #pragma unroll
      for (int j=0;j<4;j++){
        int gcol = bn0 + wn + (j<<4) + lr;
        float v = acc[i][j][r];
        if (outF) outF[grow*D_MODEL + gcol] = v;
        else      oB [grow*D_MODEL + gcol] = f2b(v);
      }
    }
  }
}

// ---------------- fused RMSNorm + RoPE on Q and K (f32, in place) ----------------
// one wave per (token,head); lane = head-dim element.
__global__ __launch_bounds__(256) void rmsrope(float* __restrict__ Q, float* __restrict__ K,
                                               const float* __restrict__ qw, const float* __restrict__ kw)
{
  const int gtid = blockIdx.x*256 + threadIdx.x;
  const int wave = gtid >> 6;          // 0..65535
  const int lane = gtid & 63;
  const int row  = wave >> 4;          // 0..4095 (b*T + t)
  const int h    = wave & 15;
  const int t    = row & (T_SEQ-1);
  const int addr = row*D_MODEL + h*HD + lane;

  const int fi = lane & 31;
  const float inv_freq = powf(10000.0f, -(float)fi * (1.0f/32.0f));
  float sn, cs;
  sincosf((float)t * inv_freq, &sn, &cs);

  {
    float x = Q[addr];
    float ss = x*x;
    #pragma unroll
    for (int off=32; off>=1; off>>=1) ss += __shfl_xor(ss, off, 64);
    float rms = rsqrtf(ss*(1.0f/64.0f) + 1e-6f);
    float xn = x*rms*qw[lane];
    float pr = __shfl_xor(xn, 32, 64);
    Q[addr] = (lane<32) ? (xn*cs - pr*sn) : (xn*cs + pr*sn);
  }
  {
    float x = K[addr];
    float ss = x*x;
    #pragma unroll
    for (int off=32; off>=1; off>>=1) ss += __shfl_xor(ss, off, 64);
    float rms = rsqrtf(ss*(1.0f/64.0f) + 1e-6f);
    float xn = x*rms*kw[lane];
    float pr = __shfl_xor(xn, 32, 64);
    K[addr] = (lane<32) ? (xn*cs - pr*sn) : (xn*cs + pr*sn);
  }
}

// ---------------- flash attention: block = (qt, h, b), 64 q-rows ----------------
__global__ __launch_bounds__(256) void attn64(const float* __restrict__ Qf, const float* __restrict__ Kf,
                                              const u16* __restrict__ Vb, u16* __restrict__ Ob)
{
  __shared__ __align__(16) float sQ [64*68];
  __shared__ __align__(16) float sKP[64*68];   // K tile, reused for P
  __shared__ __align__(16) float sV [64*68];
  const int tid = threadIdx.x;
  const int qt = blockIdx.x, h = blockIdx.y, b = blockIdx.z;
  const int base = b*T_SEQ*D_MODEL + h*HD;

  // stage Q tile, pre-scaled by 1/sqrt(64)
  const float* Qb = Qf + base + qt*64*D_MODEL;
  #pragma unroll
  for (int i=0;i<4;i++){
    int c = tid + (i<<8);
    int row = c>>4, c4 = (c&15)<<2;
    f32x4 v = *(const f32x4*)(Qb + row*D_MODEL + c4);
    v *= 0.125f;
    *(f32x4*)(sQ + row*68 + c4) = v;
  }

  const int r0 = (tid>>4)<<2;   // 4 owned S/O rows
  const int c0 = (tid&15)<<2;   // 4 owned S cols / O dims
  float o[4][4];
  float m_[4], l_[4];
  #pragma unroll
  for (int i=0;i<4;i++){
    m_[i] = -1e30f; l_[i] = 0.f;
    #pragma unroll
    for (int j=0;j<4;j++) o[i][j] = 0.f;
  }

  for (int kt=0; kt<=qt; ++kt){
    const float* Kb = Kf + base + kt*64*D_MODEL;
    #pragma unroll
    for (int i=0;i<4;i++){
      int c = tid + (i<<8);
      int row=c>>4, c4=(c&15)<<2;
      *(f32x4*)(sKP + row*68 + c4) = *(const f32x4*)(Kb + row*D_MODEL + c4);
    }
    const u16* Vp = Vb + base + kt*64*D_MODEL;
    #pragma unroll
    for (int i=0;i<2;i++){
      int c = tid + (i<<8);
      int row=c>>3, c8=(c&7)<<3;
      u32x4 pk = *(const u32x4*)(Vp + row*D_MODEL + c8);
      f32x4 lo, hi;
      lo[0]=b2f((u16)(pk[0]&0xffff)); lo[1]=b2f((u16)(pk[0]>>16));
      lo[2]=b2f((u16)(pk[1]&0xffff)); lo[3]=b2f((u16)(pk[1]>>16));
      hi[0]=b2f((u16)(pk[2]&0xffff)); hi[1]=b2f((u16)(pk[2]>>16));
      hi[2]=b2f((u16)(pk[3]&0xffff)); hi[3]=b2f((u16)(pk[3]>>16));
      *(f32x4*)(sV + row*68 + c8)     = lo;
      *(f32x4*)(sV + row*68 + c8 + 4) = hi;
    }
    __syncthreads();

    // S = Q K^T  (4x4 per thread)
    float s[4][4];
    #pragma unroll
    for (int i=0;i<4;i++)
      #pragma unroll
      for (int j=0;j<4;j++) s[i][j] = 0.f;
    for (int d4=0; d4<16; ++d4){
      f32x4 qa[4], ka[4];
      #pragma unroll
      for (int i=0;i<4;i++) qa[i] = *(const f32x4*)(sQ  + (r0+i)*68 + (d4<<2));
      #pragma unroll
      for (int j=0;j<4;j++) ka[j] = *(const f32x4*)(sKP + (c0+j)*68 + (d4<<2));
      #pragma unroll
      for (int i=0;i<4;i++)
        #pragma unroll
        for (int j=0;j<4;j++)
          s[i][j] += qa[i][0]*ka[j][0] + qa[i][1]*ka[j][1] + qa[i][2]*ka[j][2] + qa[i][3]*ka[j][3];
    }
    if (kt==qt){
      #pragma unroll
      for (int i=0;i<4;i++)
        #pragma unroll
        for (int j=0;j<4;j++)
          if (c0+j > r0+i) s[i][j] = -1e30f;
    }

    // online softmax (row owners = 16 consecutive lanes)
    float alpha[4];
    #pragma unroll
    for (int i=0;i<4;i++){
      float tm = fmaxf(fmaxf(s[i][0],s[i][1]), fmaxf(s[i][2],s[i][3]));
      #pragma unroll
      for (int off=8; off>=1; off>>=1) tm = fmaxf(tm, __shfl_xor(tm, off, 64));
      float mn = fmaxf(m_[i], tm);
      alpha[i] = expf(m_[i]-mn);
      float rs = 0.f;
      #pragma unroll
      for (int j=0;j<4;j++){ float p = expf(s[i][j]-mn); s[i][j]=p; rs+=p; }
      #pragma unroll
      for (int off=8; off>=1; off>>=1) rs += __shfl_xor(rs, off, 64);
      l_[i] = l_[i]*alpha[i] + rs;
      m_[i] = mn;
    }
    __syncthreads();   // everyone done reading K tile
    #pragma unroll
    for (int i=0;i<4;i++){
      f32x4 p4 = {s[i][0], s[i][1], s[i][2], s[i][3]};
      *(f32x4*)(sKP + (r0+i)*68 + c0) = p4;
      #pragma unroll
      for (int j=0;j<4;j++) o[i][j] *= alpha[i];
    }
    __syncthreads();   // P visible

    // O += P V
    for (int c4=0; c4<16; ++c4){
      f32x4 pa[4], va[4];
      #pragma unroll
      for (int i=0;i<4;i++) pa[i] = *(const f32x4*)(sKP + (r0+i)*68 + (c4<<2));
      #pragma unroll
      for (int k=0;k<4;k++) va[k] = *(const f32x4*)(sV + ((c4<<2)+k)*68 + c0);
      #pragma unroll
      for (int i=0;i<4;i++)
        #pragma unroll
        for (int j=0;j<4;j++)
          o[i][j] += pa[i][0]*va[0][j] + pa[i][1]*va[1][j] + pa[i][2]*va[2][j] + pa[i][3]*va[3][j];
    }
    __syncthreads();   // before next staging overwrites sKP/sV
  }

  u16* Op = Ob + base + qt*64*D_MODEL;
  #pragma unroll
  for (int i=0;i<4;i++){
    float inv = 1.0f / l_[i];
    u16x4 st;
    st[0]=f2b(o[i][0]*inv); st[1]=f2b(o[i][1]*inv);
    st[2]=f2b(o[i][2]*inv); st[3]=f2b(o[i][3]*inv);
    *(u16x4*)(Op + (r0+i)*D_MODEL + c0) = st;
  }
}

extern "C" void kernel_launch(void* const* d_in, const int* in_sizes, int n_in,
                              void* d_out, int out_size, void* d_ws, size_t ws_size,
                              hipStream_t stream)
{
  const float* X  = (const float*)d_in[0];
  const float* Wq = (const float*)d_in[1];
  const float* Wk = (const float*)d_in[2];
  const float* Wv = (const float*)d_in[3];
  const float* Wo = (const float*)d_in[4];
  const float* qw = (const float*)d_in[5];
  const float* kw = (const float*)d_in[6];

  char* ws = (char*)d_ws;
  const size_t MB = 1024*1024;
  u16*   WqT = (u16*)(ws + 0*MB);
  u16*   WkT = (u16*)(ws + 2*MB);
  u16*   WvT = (u16*)(ws + 4*MB);
  u16*   WoT = (u16*)(ws + 6*MB);
  u16*   Xb  = (u16*)(ws + 8*MB);    // 8 MB  (4096x1024 bf16)
  float* Qf  = (float*)(ws + 16*MB); // 16 MB
  float* Kf  = (float*)(ws + 32*MB); // 16 MB
  u16*   Vb  = (u16*)(ws + 48*MB);   // 8 MB
  u16*   AO  = (u16*)(ws + 56*MB);   // 8 MB  -> total 64 MB

  f32_to_bf16<<<dim3(4096), 256, 0, stream>>>(X, Xb);
  transpose_w<<<dim3(32,32,4), dim3(32,8), 0, stream>>>(Wq,Wk,Wv,Wo, WqT,WkT,WvT,WoT);
  gemm128<<<dim3(8,32,3), 256, 0, stream>>>(Xb, WqT, WkT, WvT, Qf, Kf, Vb);
  rmsrope<<<dim3(16384), 256, 0, stream>>>(Qf, Kf, qw, kw);
  attn64<<<dim3(32,16,2), 256, 0, stream>>>(Qf, Kf, Vb, AO);
  gemm128<<<dim3(8,32,1), 256, 0, stream>>>(AO, WoT, WoT, WoT, (float*)d_out, nullptr, nullptr);
}

// Round 3
// 292.096 us; speedup vs baseline: 4.2453x; 4.2453x over previous
//
#include <hip/hip_runtime.h>

typedef unsigned short u16;
typedef unsigned int   u32;
typedef __bf16 bf16x8 __attribute__((ext_vector_type(8)));
typedef float  f32x4  __attribute__((ext_vector_type(4)));
typedef u32    u32x4  __attribute__((ext_vector_type(4)));
typedef u16    u16x4  __attribute__((ext_vector_type(4)));

#define D_MODEL 1024
#define T_SEQ   2048
#define NH      16
#define HD      64

__device__ __forceinline__ float b2f(u16 u){ return __uint_as_float(((u32)u)<<16); }
__device__ __forceinline__ u16 f2b(float f){
  u32 x = __float_as_uint(f);
  x += 0x7fffu + ((x>>16)&1u);
  return (u16)(x>>16);
}

// ---------------- f32 -> bf16 elementwise convert (X) ----------------
__global__ __launch_bounds__(256) void f32_to_bf16(const float* __restrict__ src, u16* __restrict__ dst)
{
  const int i = (blockIdx.x*256 + threadIdx.x)<<2;
  f32x4 v = *(const f32x4*)(src + i);
  u16x4 o;
  o[0]=f2b(v[0]); o[1]=f2b(v[1]); o[2]=f2b(v[2]); o[3]=f2b(v[3]);
  *(u16x4*)(dst + i) = o;
}

// ---------------- weight transpose+convert: WT[n][k] = bf16(W[k][n]) ----------------
__global__ void transpose_w(const float* __restrict__ W0, const float* __restrict__ W1,
                            const float* __restrict__ W2, const float* __restrict__ W3,
                            u16* __restrict__ T0, u16* __restrict__ T1,
                            u16* __restrict__ T2, u16* __restrict__ T3)
{
  __shared__ u16 s[32][33];
  const int z = blockIdx.z;
  const float* src = (z==0)?W0:(z==1)?W1:(z==2)?W2:W3;
  u16*         dst = (z==0)?T0:(z==1)?T1:(z==2)?T2:T3;
  const int x = threadIdx.x, y = threadIdx.y;
  const int r0 = blockIdx.y*32, c0 = blockIdx.x*32;
  #pragma unroll
  for (int r=0;r<4;r++) s[y + r*8][x] = f2b(src[(r0 + y + r*8)*D_MODEL + c0 + x]);
  __syncthreads();
  #pragma unroll
  for (int r=0;r<4;r++) dst[(c0 + y + r*8)*D_MODEL + r0 + x] = s[x][y + r*8];
}

// ---------------- 128x128 MFMA GEMM:  C[4096][1024] = A[4096][1024] * Bt^T ----------
// A, Bt bf16 (Bt is N x K row-major). Outputs per z:
//  z==0: oF (f32) if non-null else oQ (bf16, normal layout)
//  z==1: oK (bf16, normal layout)
//  z==2: oVt (bf16, TRANSPOSED per-head: Vt[((b*NH+h)*HD+d)*T + t])
__global__ __launch_bounds__(256) void gemm128(
    const u16* __restrict__ A,
    const u16* __restrict__ B0, const u16* __restrict__ B1, const u16* __restrict__ B2,
    float* __restrict__ oF, u16* __restrict__ oQ, u16* __restrict__ oK, u16* __restrict__ oVt)
{
  __shared__ __align__(16) u16 sA[128*40];
  __shared__ __align__(16) u16 sB[128*40];
  const int z = blockIdx.z;
  const u16* Bt = (z==0)?B0:(z==1)?B1:B2;

  const int tid = threadIdx.x;
  const int bm0 = blockIdx.y<<7, bn0 = blockIdx.x<<7;
  const int lane = tid & 63;
  const int wm = ((tid>>7)&1)<<6;   // wave row (0/64)
  const int wn = ((tid>>6)&1)<<6;   // wave col (0/64)
  const int q8 = (lane>>4)<<3;      // quad*8 (k offset in fragment)
  const int lr = lane & 15;

  const f32x4 z4 = {0.f,0.f,0.f,0.f};
  f32x4 acc[4][4];
  #pragma unroll
  for (int i=0;i<4;i++)
    #pragma unroll
    for (int j=0;j<4;j++) acc[i][j] = z4;

  for (int kt=0; kt<D_MODEL; kt+=32){
    #pragma unroll
    for (int i=0;i<2;i++){
      int c = tid + (i<<8);               // 512 chunks of 8 bf16
      int row = c>>2, col8 = (c&3)<<3;
      *(u32x4*)(sA + row*40 + col8) = *(const u32x4*)(A  + (bm0+row)*D_MODEL + kt + col8);
      *(u32x4*)(sB + row*40 + col8) = *(const u32x4*)(Bt + (bn0+row)*D_MODEL + kt + col8);
    }
    __syncthreads();
    bf16x8 af[4], bfr[4];
    #pragma unroll
    for (int i=0;i<4;i++) af[i]  = *(const bf16x8*)(sA + (wm + (i<<4) + lr)*40 + q8);
    #pragma unroll
    for (int j=0;j<4;j++) bfr[j] = *(const bf16x8*)(sB + (wn + (j<<4) + lr)*40 + q8);
    #pragma unroll
    for (int i=0;i<4;i++)
      #pragma unroll
      for (int j=0;j<4;j++)
        acc[i][j] = __builtin_amdgcn_mfma_f32_16x16x32_bf16(af[i], bfr[j], acc[i][j], 0, 0, 0);
    __syncthreads();
  }

  const int rq = (lane>>4)<<2;
  if (z==2){
    // transposed V write: Vt[((b*NH+h)*HD+d)*T + t]
    #pragma unroll
    for (int i=0;i<4;i++){
      int row0 = bm0 + wm + (i<<4) + rq;        // token base (4 consecutive)
      int bb = row0 >> 11, tt = row0 & (T_SEQ-1);
      #pragma unroll
      for (int j=0;j<4;j++){
        int col = bn0 + wn + (j<<4) + lr;       // h*64 + d
        int hh = col >> 6, dd = col & 63;
        u16x4 st;
        #pragma unroll
        for (int r=0;r<4;r++) st[r] = f2b(acc[i][j][r]);
        *(u16x4*)(oVt + ((bb*NH + hh)*HD + dd)*T_SEQ + tt) = st;
      }
    }
  } else {
    u16* oB = (z==0) ? oQ : oK;
    #pragma unroll
    for (int i=0;i<4;i++){
      #pragma unroll
      for (int r=0;r<4;r++){
        int grow = bm0 + wm + (i<<4) + rq + r;
        #pragma unroll
        for (int j=0;j<4;j++){
          int gcol = bn0 + wn + (j<<4) + lr;
          float v = acc[i][j][r];
          if (z==0 && oF) oF[grow*D_MODEL + gcol] = v;
          else            oB[grow*D_MODEL + gcol] = f2b(v);
        }
      }
    }
  }
}

// ---------------- fused RMSNorm + RoPE on Q and K (bf16, in place) ----------------
// one wave per (token,head); lane = head-dim element. Q gets *0.125 (1/sqrt(hd)).
__global__ __launch_bounds__(256) void rmsrope(u16* __restrict__ Q, u16* __restrict__ K,
                                               const float* __restrict__ qw, const float* __restrict__ kw)
{
  const int gtid = blockIdx.x*256 + threadIdx.x;
  const int wave = gtid >> 6;          // 0..65535
  const int lane = gtid & 63;
  const int row  = wave >> 4;          // 0..4095 (b*T + t)
  const int h    = wave & 15;
  const int t    = row & (T_SEQ-1);
  const int addr = row*D_MODEL + h*HD + lane;

  const int fi = lane & 31;
  const float inv_freq = powf(10000.0f, -(float)fi * (1.0f/32.0f));
  float sn, cs;
  sincosf((float)t * inv_freq, &sn, &cs);

  {
    float x = b2f(Q[addr]);
    float ss = x*x;
    #pragma unroll
    for (int off=32; off>=1; off>>=1) ss += __shfl_xor(ss, off, 64);
    float rms = rsqrtf(ss*(1.0f/64.0f) + 1e-6f);
    float xn = x*rms*qw[lane];
    float pr = __shfl_xor(xn, 32, 64);
    float ro = (lane<32) ? (xn*cs - pr*sn) : (xn*cs + pr*sn);
    Q[addr] = f2b(ro * 0.125f);
  }
  {
    float x = b2f(K[addr]);
    float ss = x*x;
    #pragma unroll
    for (int off=32; off>=1; off>>=1) ss += __shfl_xor(ss, off, 64);
    float rms = rsqrtf(ss*(1.0f/64.0f) + 1e-6f);
    float xn = x*rms*kw[lane];
    float pr = __shfl_xor(xn, 32, 64);
    K[addr] = f2b((lane<32) ? (xn*cs - pr*sn) : (xn*cs + pr*sn));
  }
}

// ---------------- MFMA flash attention ----------------
// block = (h, b, qt'), 64 q-rows per block, 4 waves x 16 rows.
// Qb/Kb: [b*T+t][h*64+d] bf16 (Q pre-scaled by 0.125). Vt: [((b*NH+h)*HD+d)*T + t] bf16.
__global__ __launch_bounds__(256) void attn_mfma(const u16* __restrict__ Qb, const u16* __restrict__ Kb,
                                                 const u16* __restrict__ Vt, u16* __restrict__ AO)
{
  __shared__ __align__(16) u16 sK [64*68];   // [key][dim]
  __shared__ __align__(16) u16 sVT[64*68];   // [dim][key]
  __shared__ __align__(16) u16 sP [4*16*68]; // per-wave P tile [row][key]
  const int tid = threadIdx.x;
  const int h  = blockIdx.x, b = blockIdx.y;
  const int qt = 31 - blockIdx.z;            // largest-first dispatch
  const int w = tid>>6, lane = tid&63;
  const int quad = lane>>4, lr = lane&15;
  const int q8 = quad<<3;

  // Q fragments for this wave's 16 rows (row = lane&15)
  const u16* Qrow = Qb + (b*T_SEQ + qt*64 + w*16 + lr)*D_MODEL + h*HD;
  bf16x8 qf0 = *(const bf16x8*)(Qrow + q8);
  bf16x8 qf1 = *(const bf16x8*)(Qrow + 32 + q8);

  f32x4 o[4];
  float m_[4], l_[4];
  #pragma unroll
  for (int r=0;r<4;r++){ m_[r] = -1e30f; l_[r] = 0.f; }
  const f32x4 z4 = {0.f,0.f,0.f,0.f};
  #pragma unroll
  for (int nt=0;nt<4;nt++) o[nt] = z4;

  u16* myP = sP + w*16*68;

  for (int kt=0; kt<=qt; ++kt){
    // stage K tile [64 key][64 dim] and VT tile [64 dim][64 key]
    #pragma unroll
    for (int i=0;i<2;i++){
      int idx = tid + (i<<8);
      int row = idx>>3, c8 = (idx&7)<<3;
      *(u32x4*)(sK + row*68 + c8) = *(const u32x4*)(Kb + (b*T_SEQ + kt*64 + row)*D_MODEL + h*HD + c8);
    }
    #pragma unroll
    for (int i=0;i<2;i++){
      int idx = tid + (i<<8);
      int row = idx>>3, c8 = (idx&7)<<3;
      *(u32x4*)(sVT + row*68 + c8) = *(const u32x4*)(Vt + ((b*NH + h)*HD + row)*T_SEQ + kt*64 + c8);
    }
    __syncthreads();

    // S = Q K^T : 4 col-tiles of 16 keys
    f32x4 s4[4];
    #pragma unroll
    for (int ct=0; ct<4; ++ct){
      bf16x8 k0 = *(const bf16x8*)(sK + (ct*16 + lr)*68 + q8);
      bf16x8 k1 = *(const bf16x8*)(sK + (ct*16 + lr)*68 + 32 + q8);
      f32x4 acc = z4;
      acc = __builtin_amdgcn_mfma_f32_16x16x32_bf16(qf0, k0, acc, 0,0,0);
      acc = __builtin_amdgcn_mfma_f32_16x16x32_bf16(qf1, k1, acc, 0,0,0);
      s4[ct] = acc;
    }

    if (kt == qt){
      // causal mask within diagonal tile (relative row/col)
      #pragma unroll
      for (int ct=0; ct<4; ++ct){
        int col = ct*16 + lr;
        #pragma unroll
        for (int r=0;r<4;r++){
          int row = w*16 + quad*4 + r;
          if (col > row) s4[ct][r] = -1e30f;
        }
      }
    }

    // online softmax per row (row owners = 16 lanes of a quad)
    float alpha[4];
    #pragma unroll
    for (int r=0;r<4;r++){
      float tm = fmaxf(fmaxf(s4[0][r],s4[1][r]), fmaxf(s4[2][r],s4[3][r]));
      #pragma unroll
      for (int off=8; off>=1; off>>=1) tm = fmaxf(tm, __shfl_xor(tm, off, 64));
      float mn = fmaxf(m_[r], tm);
      alpha[r] = __expf(m_[r] - mn);
      float rs = 0.f;
      #pragma unroll
      for (int ct=0; ct<4; ++ct){ float p = __expf(s4[ct][r]-mn); s4[ct][r] = p; rs += p; }
      #pragma unroll
      for (int off=8; off>=1; off>>=1) rs += __shfl_xor(rs, off, 64);
      l_[r] = l_[r]*alpha[r] + rs;
      m_[r] = mn;
    }

    // P -> per-wave LDS (C/D layout -> A-operand layout round trip)
    #pragma unroll
    for (int ct=0; ct<4; ++ct)
      #pragma unroll
      for (int r=0;r<4;r++)
        myP[(quad*4 + r)*68 + ct*16 + lr] = f2b(s4[ct][r]);

    #pragma unroll
    for (int nt=0;nt<4;nt++)
      #pragma unroll
      for (int r=0;r<4;r++) o[nt][r] *= alpha[r];

    // O += P V  (k-dim = key, 2 steps of 32)
    #pragma unroll
    for (int s=0;s<2;s++){
      bf16x8 pf = *(const bf16x8*)(myP + lr*68 + s*32 + q8);
      #pragma unroll
      for (int nt=0;nt<4;nt++){
        bf16x8 vf = *(const bf16x8*)(sVT + (nt*16 + lr)*68 + s*32 + q8);
        o[nt] = __builtin_amdgcn_mfma_f32_16x16x32_bf16(pf, vf, o[nt], 0,0,0);
      }
    }
    __syncthreads();   // before next tile staging overwrites sK/sVT
  }

  // epilogue: O /= l, write bf16
  const int rowg = b*T_SEQ + qt*64 + w*16 + quad*4;
  #pragma unroll
  for (int r=0;r<4;r++){
    float inv = 1.0f / l_[r];
    #pragma unroll
    for (int nt=0;nt<4;nt++)
      AO[(rowg + r)*D_MODEL + h*HD + nt*16 + lr] = f2b(o[nt][r]*inv);
  }
}

extern "C" void kernel_launch(void* const* d_in, const int* in_sizes, int n_in,
                              void* d_out, int out_size, void* d_ws, size_t ws_size,
                              hipStream_t stream)
{
  const float* X  = (const float*)d_in[0];
  const float* Wq = (const float*)d_in[1];
  const float* Wk = (const float*)d_in[2];
  const float* Wv = (const float*)d_in[3];
  const float* Wo = (const float*)d_in[4];
  const float* qw = (const float*)d_in[5];
  const float* kw = (const float*)d_in[6];

  char* ws = (char*)d_ws;
  const size_t MB = 1024*1024;
  u16* WqT = (u16*)(ws + 0*MB);
  u16* WkT = (u16*)(ws + 2*MB);
  u16* WvT = (u16*)(ws + 4*MB);
  u16* WoT = (u16*)(ws + 6*MB);
  u16* Xb  = (u16*)(ws + 8*MB);    // 8 MB (4096x1024 bf16)
  u16* Qb  = (u16*)(ws + 16*MB);   // 8 MB
  u16* Kb  = (u16*)(ws + 24*MB);   // 8 MB
  u16* Vt  = (u16*)(ws + 32*MB);   // 8 MB (transposed per-head)
  u16* AO  = (u16*)(ws + 40*MB);   // 8 MB  -> 48 MB total

  f32_to_bf16<<<dim3(4096), 256, 0, stream>>>(X, Xb);
  transpose_w<<<dim3(32,32,4), dim3(32,8), 0, stream>>>(Wq,Wk,Wv,Wo, WqT,WkT,WvT,WoT);
  gemm128<<<dim3(8,32,3), 256, 0, stream>>>(Xb, WqT, WkT, WvT, nullptr, Qb, Kb, Vt);
  rmsrope<<<dim3(16384), 256, 0, stream>>>(Qb, Kb, qw, kw);
  attn_mfma<<<dim3(NH, 2, 32), 256, 0, stream>>>(Qb, Kb, Vt, AO);
  gemm128<<<dim3(8,32,1), 256, 0, stream>>>(AO, WoT, WoT, WoT, (float*)d_out, nullptr, nullptr, nullptr);
}

// Round 5
// 230.185 us; speedup vs baseline: 5.3872x; 1.2690x over previous
//
#include <hip/hip_runtime.h>

typedef unsigned short u16;
typedef unsigned int   u32;
typedef __bf16 bf16x8 __attribute__((ext_vector_type(8)));
typedef float  f32x4  __attribute__((ext_vector_type(4)));
typedef u32    u32x4  __attribute__((ext_vector_type(4)));
typedef u16    u16x4  __attribute__((ext_vector_type(4)));

#define D_MODEL 1024
#define T_SEQ   2048
#define NH      16
#define HD      64

__device__ __forceinline__ float b2f(u16 u){ return __uint_as_float(((u32)u)<<16); }
__device__ __forceinline__ u16 f2b(float f){
  u32 x = __float_as_uint(f);
  x += 0x7fffu + ((x>>16)&1u);
  return (u16)(x>>16);
}

// async global->LDS, 16B per lane. lptr must be wave-uniform; HW adds lane*16.
__device__ __forceinline__ void gll16(const void* g, void* l){
  __builtin_amdgcn_global_load_lds((const __attribute__((address_space(1))) unsigned int*)g,
                                   (__attribute__((address_space(3))) unsigned int*)l, 16, 0, 0);
}

// ---------------- f32 -> bf16 elementwise convert (X) ----------------
__global__ __launch_bounds__(256) void f32_to_bf16(const float* __restrict__ src, u16* __restrict__ dst)
{
  const int i = (blockIdx.x*256 + threadIdx.x)<<2;
  f32x4 v = *(const f32x4*)(src + i);
  u16x4 o;
  o[0]=f2b(v[0]); o[1]=f2b(v[1]); o[2]=f2b(v[2]); o[3]=f2b(v[3]);
  *(u16x4*)(dst + i) = o;
}

// ---------------- weight transpose+convert: WT[n][k] = bf16(W[k][n]) ----------------
__global__ void transpose_w(const float* __restrict__ W0, const float* __restrict__ W1,
                            const float* __restrict__ W2, const float* __restrict__ W3,
                            u16* __restrict__ T0, u16* __restrict__ T1,
                            u16* __restrict__ T2, u16* __restrict__ T3)
{
  __shared__ u16 s[32][33];
  const int z = blockIdx.z;
  const float* src = (z==0)?W0:(z==1)?W1:(z==2)?W2:W3;
  u16*         dst = (z==0)?T0:(z==1)?T1:(z==2)?T2:T3;
  const int x = threadIdx.x, y = threadIdx.y;
  const int r0 = blockIdx.y*32, c0 = blockIdx.x*32;
  #pragma unroll
  for (int r=0;r<4;r++) s[y + r*8][x] = f2b(src[(r0 + y + r*8)*D_MODEL + c0 + x]);
  __syncthreads();
  #pragma unroll
  for (int r=0;r<4;r++) dst[(c0 + y + r*8)*D_MODEL + r0 + x] = s[x][y + r*8];
}

// ---------------- 128x128 MFMA GEMM with global_load_lds staging ----------
// A[4096][1024] bf16, Bt (NxK) bf16. LDS tiles stored as swizzled 16B slots:
// slot(row,c) = row*4 + (c ^ ((row>>1)&3)), c = 16B-chunk (8 bf16) within BK=32.
// z==0: out f32 (oF) if non-null else bf16 oQ; z==1: bf16 oK; z==2: transposed Vt.
__global__ __launch_bounds__(256) void gemm128(
    const u16* __restrict__ A,
    const u16* __restrict__ B0, const u16* __restrict__ B1, const u16* __restrict__ B2,
    float* __restrict__ oF, u16* __restrict__ oQ, u16* __restrict__ oK, u16* __restrict__ oVt)
{
  __shared__ __align__(16) u16 sA[512*8];   // 512 slots x 16B = 8KB
  __shared__ __align__(16) u16 sB[512*8];
  const int z = blockIdx.z;
  const u16* Bt = (z==0)?B0:(z==1)?B1:B2;

  const int tid = threadIdx.x;
  const int bm0 = blockIdx.y<<7, bn0 = blockIdx.x<<7;
  const int lane = tid & 63;
  const int w  = tid>>6;
  const int wm = (w>>1)<<6;
  const int wn = (w&1)<<6;
  const int quad = lane>>4, lr = lane&15;

  // staging decode: issue i covers slots i*256 + w*64 + lane
  const int s0 = w*64 + lane, s1 = 256 + w*64 + lane;
  const int rA0 = s0>>2, cA0 = (s0&3)^((rA0>>1)&3);
  const int rA1 = s1>>2, cA1 = (s1&3)^((rA1>>1)&3);
  u16* ldsA0 = sA + (w*64)*8;        // wave-uniform
  u16* ldsA1 = sA + (256 + w*64)*8;
  u16* ldsB0 = sB + (w*64)*8;
  u16* ldsB1 = sB + (256 + w*64)*8;
  const u16* gA0 = A  + (bm0+rA0)*D_MODEL + cA0*8;
  const u16* gA1 = A  + (bm0+rA1)*D_MODEL + cA1*8;
  const u16* gB0 = Bt + (bn0+rA0)*D_MODEL + cA0*8;
  const u16* gB1 = Bt + (bn0+rA1)*D_MODEL + cA1*8;

  const int cfr = (lr>>1)&3;   // frag-read swizzle component

  const f32x4 z4 = {0.f,0.f,0.f,0.f};
  f32x4 acc[4][4];
  #pragma unroll
  for (int i=0;i<4;i++)
    #pragma unroll
    for (int j=0;j<4;j++) acc[i][j] = z4;

  for (int kt=0; kt<D_MODEL; kt+=32){
    gll16(gA0 + kt, ldsA0);
    gll16(gA1 + kt, ldsA1);
    gll16(gB0 + kt, ldsB0);
    gll16(gB1 + kt, ldsB1);
    __syncthreads();
    bf16x8 af[4], bfr[4];
    const int cq = (quad ^ cfr)<<3;
    #pragma unroll
    for (int i=0;i<4;i++) af[i]  = *(const bf16x8*)(sA + (wm + (i<<4) + lr)*32 + cq);
    #pragma unroll
    for (int j=0;j<4;j++) bfr[j] = *(const bf16x8*)(sB + (wn + (j<<4) + lr)*32 + cq);
    #pragma unroll
    for (int i=0;i<4;i++)
      #pragma unroll
      for (int j=0;j<4;j++)
        acc[i][j] = __builtin_amdgcn_mfma_f32_16x16x32_bf16(af[i], bfr[j], acc[i][j], 0, 0, 0);
    __syncthreads();
  }

  const int rq = quad<<2;
  if (z==2){
    #pragma unroll
    for (int i=0;i<4;i++){
      int row0 = bm0 + wm + (i<<4) + rq;        // token base (4 consecutive)
      int bb = row0 >> 11, tt = row0 & (T_SEQ-1);
      #pragma unroll
      for (int j=0;j<4;j++){
        int col = bn0 + wn + (j<<4) + lr;       // h*64 + d
        int hh = col >> 6, dd = col & 63;
        u16x4 st;
        #pragma unroll
        for (int r=0;r<4;r++) st[r] = f2b(acc[i][j][r]);
        *(u16x4*)(oVt + ((bb*NH + hh)*HD + dd)*T_SEQ + tt) = st;
      }
    }
  } else {
    u16* oB = (z==0) ? oQ : oK;
    #pragma unroll
    for (int i=0;i<4;i++){
      #pragma unroll
      for (int r=0;r<4;r++){
        int grow = bm0 + wm + (i<<4) + rq + r;
        #pragma unroll
        for (int j=0;j<4;j++){
          int gcol = bn0 + wn + (j<<4) + lr;
          float v = acc[i][j][r];
          if (z==0 && oF) oF[grow*D_MODEL + gcol] = v;
          else            oB[grow*D_MODEL + gcol] = f2b(v);
        }
      }
    }
  }
}

// ---------------- fused RMSNorm + RoPE on Q and K (bf16, in place) ----------------
__global__ __launch_bounds__(256) void rmsrope(u16* __restrict__ Q, u16* __restrict__ K,
                                               const float* __restrict__ qw, const float* __restrict__ kw)
{
  const int gtid = blockIdx.x*256 + threadIdx.x;
  const int wave = gtid >> 6;
  const int lane = gtid & 63;
  const int row  = wave >> 4;          // b*T + t
  const int h    = wave & 15;
  const int t    = row & (T_SEQ-1);
  const int addr = row*D_MODEL + h*HD + lane;

  const int fi = lane & 31;
  // 10000^(-fi/32) = exp(-fi * ln(10000)/32)
  const float inv_freq = __expf(-(float)fi * 0.28782313662f);
  float sn, cs;
  __sincosf((float)t * inv_freq, &sn, &cs);

  {
    float x = b2f(Q[addr]);
    float ss = x*x;
    #pragma unroll
    for (int off=32; off>=1; off>>=1) ss += __shfl_xor(ss, off, 64);
    float rms = rsqrtf(ss*(1.0f/64.0f) + 1e-6f);
    float xn = x*rms*qw[lane];
    float pr = __shfl_xor(xn, 32, 64);
    float ro = (lane<32) ? (xn*cs - pr*sn) : (xn*cs + pr*sn);
    Q[addr] = f2b(ro * 0.125f);     // fold 1/sqrt(hd)
  }
  {
    float x = b2f(K[addr]);
    float ss = x*x;
    #pragma unroll
    for (int off=32; off>=1; off>>=1) ss += __shfl_xor(ss, off, 64);
    float rms = rsqrtf(ss*(1.0f/64.0f) + 1e-6f);
    float xn = x*rms*kw[lane];
    float pr = __shfl_xor(xn, 32, 64);
    K[addr] = f2b((lane<32) ? (xn*cs - pr*sn) : (xn*cs + pr*sn));
  }
}

// ---------------- MFMA flash attention, no-max softmax, dbuf gll staging ----------
// |q|2=|k|2=8 after rmsnorm (w=1) => |s|<=8; p=exp(s-8)<=1. acc init = -8.
// K/VT tiles in swizzled slots: slot(row,c) = row*8 + (c^(row&7)), c = 16B chunk.
__global__ __launch_bounds__(256) void attn_mfma(const u16* __restrict__ Qb, const u16* __restrict__ Kb,
                                                 const u16* __restrict__ Vt, u16* __restrict__ AO)
{
  __shared__ __align__(16) u16 sK [2][512*8];   // 8KB each
  __shared__ __align__(16) u16 sVT[2][512*8];
  __shared__ __align__(16) u16 sP [4][16*68];
  const int tid = threadIdx.x;
  const int h  = blockIdx.x, b = blockIdx.y;
  const int qt = 31 - blockIdx.z;            // largest-first
  const int w = tid>>6, lane = tid&63;
  const int quad = lane>>4, lr = lane&15;
  const int q8 = quad<<3;

  // staging decode
  const int s0 = w*64 + lane, s1 = 256 + w*64 + lane;
  const int r0s = s0>>3, c0s = (s0&7)^(r0s&7);
  const int r1s = s1>>3, c1s = (s1&7)^(r1s&7);
  const u16* Kbase = Kb + (b*T_SEQ)*D_MODEL + h*HD;
  const u16* Vbase = Vt + (b*NH + h)*HD*T_SEQ;
  const int ldsOff0 = (w*64)*8, ldsOff1 = (256 + w*64)*8;   // wave-uniform

  // Q fragments for this wave's 16 rows
  const u16* Qrow = Qb + (b*T_SEQ + qt*64 + w*16 + lr)*D_MODEL + h*HD;
  bf16x8 qf0 = *(const bf16x8*)(Qrow + q8);
  bf16x8 qf1 = *(const bf16x8*)(Qrow + 32 + q8);

  f32x4 o[4];
  float lp[4];
  const f32x4 z4 = {0.f,0.f,0.f,0.f};
  const f32x4 i8 = {-8.f,-8.f,-8.f,-8.f};
  #pragma unroll
  for (int r=0;r<4;r++) lp[r] = 0.f;
  #pragma unroll
  for (int nt=0;nt<4;nt++) o[nt] = z4;

  u16* myP = sP[w];

  // stage tile 0 into buffer 0
  {
    gll16(Kbase + (0*64 + r0s)*D_MODEL + c0s*8, &sK[0][ldsOff0]);
    gll16(Kbase + (0*64 + r1s)*D_MODEL + c1s*8, &sK[0][ldsOff1]);
    gll16(Vbase + r0s*T_SEQ + 0*64 + c0s*8,     &sVT[0][ldsOff0]);
    gll16(Vbase + r1s*T_SEQ + 0*64 + c1s*8,     &sVT[0][ldsOff1]);
  }
  __syncthreads();

  for (int kt=0; kt<=qt; ++kt){
    const int cur = kt&1;
    if (kt < qt){
      const int kn = kt+1, nb = cur^1;
      gll16(Kbase + (kn*64 + r0s)*D_MODEL + c0s*8, &sK[nb][ldsOff0]);
      gll16(Kbase + (kn*64 + r1s)*D_MODEL + c1s*8, &sK[nb][ldsOff1]);
      gll16(Vbase + r0s*T_SEQ + kn*64 + c0s*8,     &sVT[nb][ldsOff0]);
      gll16(Vbase + r1s*T_SEQ + kn*64 + c1s*8,     &sVT[nb][ldsOff1]);
    }

    // S = Q K^T (acc init -8)
    f32x4 s4[4];
    #pragma unroll
    for (int ct=0; ct<4; ++ct){
      const int row = ct*16 + lr;
      const int sw = row&7;
      bf16x8 k0 = *(const bf16x8*)(&sK[cur][(row*8 + (quad     ^ sw))*8]);
      bf16x8 k1 = *(const bf16x8*)(&sK[cur][(row*8 + ((4+quad) ^ sw))*8]);
      f32x4 acc = i8;
      acc = __builtin_amdgcn_mfma_f32_16x16x32_bf16(qf0, k0, acc, 0,0,0);
      acc = __builtin_amdgcn_mfma_f32_16x16x32_bf16(qf1, k1, acc, 0,0,0);
      s4[ct] = acc;
    }

    if (kt == qt){
      #pragma unroll
      for (int ct=0; ct<4; ++ct){
        int col = ct*16 + lr;
        #pragma unroll
        for (int r=0;r<4;r++)
          if (col > w*16 + quad*4 + r) s4[ct][r] = -1e30f;
      }
    }

    // p = exp(s-8); truncate to bf16 consistently for l and P
    #pragma unroll
    for (int ct=0; ct<4; ++ct){
      #pragma unroll
      for (int r=0;r<4;r++){
        float p = __expf(s4[ct][r]);
        u32 pu = __float_as_uint(p) & 0xffff0000u;
        lp[r] += __uint_as_float(pu);
        myP[(quad*4 + r)*68 + ct*16 + lr] = (u16)(pu>>16);
      }
    }

    // O += P V
    #pragma unroll
    for (int st=0; st<2; ++st){
      bf16x8 pf = *(const bf16x8*)(myP + lr*68 + st*32 + q8);
      #pragma unroll
      for (int nt=0;nt<4;nt++){
        const int row = nt*16 + lr;
        const int slot = row*8 + ((st*4+quad) ^ (row&7));
        bf16x8 vf = *(const bf16x8*)(&sVT[cur][slot*8]);
        o[nt] = __builtin_amdgcn_mfma_f32_16x16x32_bf16(pf, vf, o[nt], 0,0,0);
      }
    }
    __syncthreads();   // publishes prefetched buffer; all waves done with cur
  }

  // reduce l over the 16 lanes of each quad, write O/l
  #pragma unroll
  for (int r=0;r<4;r++){
    #pragma unroll
    for (int off=8; off>=1; off>>=1) lp[r] += __shfl_xor(lp[r], off, 64);
  }
  const int rowg = b*T_SEQ + qt*64 + w*16 + quad*4;
  #pragma unroll
  for (int r=0;r<4;r++){
    float inv = 1.0f / lp[r];
    #pragma unroll
    for (int nt=0;nt<4;nt++)
      AO[(rowg + r)*D_MODEL + h*HD + nt*16 + lr] = f2b(o[nt][r]*inv);
  }
}

extern "C" void kernel_launch(void* const* d_in, const int* in_sizes, int n_in,
                              void* d_out, int out_size, void* d_ws, size_t ws_size,
                              hipStream_t stream)
{
  const float* X  = (const float*)d_in[0];
  const float* Wq = (const float*)d_in[1];
  const float* Wk = (const float*)d_in[2];
  const float* Wv = (const float*)d_in[3];
  const float* Wo = (const float*)d_in[4];
  const float* qw = (const float*)d_in[5];
  const float* kw = (const float*)d_in[6];

  char* ws = (char*)d_ws;
  const size_t MB = 1024*1024;
  u16* WqT = (u16*)(ws + 0*MB);
  u16* WkT = (u16*)(ws + 2*MB);
  u16* WvT = (u16*)(ws + 4*MB);
  u16* WoT = (u16*)(ws + 6*MB);
  u16* Xb  = (u16*)(ws + 8*MB);
  u16* Qb  = (u16*)(ws + 16*MB);
  u16* Kb  = (u16*)(ws + 24*MB);
  u16* Vt  = (u16*)(ws + 32*MB);
  u16* AO  = (u16*)(ws + 40*MB);

  f32_to_bf16<<<dim3(4096), 256, 0, stream>>>(X, Xb);
  transpose_w<<<dim3(32,32,4), dim3(32,8), 0, stream>>>(Wq,Wk,Wv,Wo, WqT,WkT,WvT,WoT);
  gemm128<<<dim3(8,32,3), 256, 0, stream>>>(Xb, WqT, WkT, WvT, nullptr, Qb, Kb, Vt);
  rmsrope<<<dim3(16384), 256, 0, stream>>>(Qb, Kb, qw, kw);
  attn_mfma<<<dim3(NH, 2, 32), 256, 0, stream>>>(Qb, Kb, Vt, AO);
  gemm128<<<dim3(8,32,1), 256, 0, stream>>>(AO, WoT, WoT, WoT, (float*)d_out, nullptr, nullptr, nullptr);
}

// Round 6
// 204.357 us; speedup vs baseline: 6.0680x; 1.1264x over previous
//
#include <hip/hip_runtime.h>

typedef unsigned short u16;
typedef unsigned int   u32;
typedef __bf16 bf16x8 __attribute__((ext_vector_type(8)));
typedef float  f32x4  __attribute__((ext_vector_type(4)));
typedef float  f32x2  __attribute__((ext_vector_type(2)));
typedef u32    u32x4  __attribute__((ext_vector_type(4)));
typedef u16    u16x4  __attribute__((ext_vector_type(4)));

#define D_MODEL 1024
#define T_SEQ   2048
#define NH      16
#define HD      64

__device__ __forceinline__ float b2f(u16 u){ return __uint_as_float(((u32)u)<<16); }
__device__ __forceinline__ u16 f2b(float f){
  u32 x = __float_as_uint(f);
  x += 0x7fffu + ((x>>16)&1u);
  return (u16)(x>>16);
}

// async global->LDS, 16B per lane. LDS ptr wave-uniform; HW adds lane*16.
__device__ __forceinline__ void gll16(const void* g, void* l){
  __builtin_amdgcn_global_load_lds((const __attribute__((address_space(1))) unsigned int*)g,
                                   (__attribute__((address_space(3))) unsigned int*)l, 16, 0, 0);
}

// ---------------- f32 -> bf16 elementwise convert (X) ----------------
__global__ __launch_bounds__(256) void f32_to_bf16(const float* __restrict__ src, u16* __restrict__ dst)
{
  const int i = (blockIdx.x*256 + threadIdx.x)<<2;
  f32x4 v = *(const f32x4*)(src + i);
  u16x4 o;
  o[0]=f2b(v[0]); o[1]=f2b(v[1]); o[2]=f2b(v[2]); o[3]=f2b(v[3]);
  *(u16x4*)(dst + i) = o;
}

// ---------------- weight transpose+convert: WT[n][k] = bf16(W[k][n]) ----------------
__global__ void transpose_w(const float* __restrict__ W0, const float* __restrict__ W1,
                            const float* __restrict__ W2, const float* __restrict__ W3,
                            u16* __restrict__ T0, u16* __restrict__ T1,
                            u16* __restrict__ T2, u16* __restrict__ T3)
{
  __shared__ u16 s[32][33];
  const int z = blockIdx.z;
  const float* src = (z==0)?W0:(z==1)?W1:(z==2)?W2:W3;
  u16*         dst = (z==0)?T0:(z==1)?T1:(z==2)?T2:T3;
  const int x = threadIdx.x, y = threadIdx.y;
  const int r0 = blockIdx.y*32, c0 = blockIdx.x*32;
  #pragma unroll
  for (int r=0;r<4;r++) s[y + r*8][x] = f2b(src[(r0 + y + r*8)*D_MODEL + c0 + x]);
  __syncthreads();
  #pragma unroll
  for (int r=0;r<4;r++) dst[(c0 + y + r*8)*D_MODEL + r0 + x] = s[x][y + r*8];
}

// ---------------- RoPE cos/sin table: cs[(t*32+fi)*2] = {cos, sin} ----------------
__global__ __launch_bounds__(256) void rope_table(float* __restrict__ cs)
{
  const int gid = blockIdx.x*256 + threadIdx.x;   // 65536
  const int t = gid >> 5, fi = gid & 31;
  const float invf = expf(-(float)fi * 0.2878231366242558f);  // ln(1e4)/32
  float sn, cn;
  sincosf((float)t * invf, &sn, &cn);
  cs[gid*2]   = cn;
  cs[gid*2+1] = sn;
}

// ============== QKV GEMM, BK=64, fused RMSNorm+RoPE epilogue ==============
// A[4096][1024] bf16, Bt[3072][1024] bf16 (WqT|WkT|WvT stacked).
// LDS slots: slot(row,c) = row*8 + (c ^ (row&7)), c = 16B chunk (8 bf16) of BK=64.
// grid 768 1D; XCD k=id&7 owns region bn in [ (k&1)*12, +12 ), bm in [ (k>>1)*8, +8 ).
__global__ __launch_bounds__(256) void gemm_qkv(
    const u16* __restrict__ A, const u16* __restrict__ Bt,
    const float* __restrict__ qw, const float* __restrict__ kw,
    const float* __restrict__ cs,
    u16* __restrict__ Qb, u16* __restrict__ Kb, u16* __restrict__ Vt)
{
  __shared__ __align__(16) u16 sA[1024*8];   // 16 KB
  __shared__ __align__(16) u16 sB[1024*8];
  const int id = blockIdx.x;
  const int xcd = id & 7, slot = id >> 3;     // slot 0..95
  const int bn = (xcd & 1)*12 + (slot % 12);  // 0..23
  const int bm = (xcd >> 1)*8 + (slot / 12);  // 0..31
  const int bm0 = bm<<7, bn0 = bn<<7;

  const int tid = threadIdx.x;
  const int lane = tid & 63;
  const int w  = tid>>6;
  const int wm = (w>>1)<<6;
  const int wn = (w&1)<<6;
  const int quad = lane>>4, lr = lane&15;
  const int swl = lr & 7;

  // staging decode: issue i covers slots i*256 + tid
  int rS[4], cS[4];
  #pragma unroll
  for (int i=0;i<4;i++){
    int s = i*256 + tid;
    rS[i] = s>>3;
    cS[i] = (s&7) ^ (rS[i]&7);
  }

  const f32x4 z4 = {0.f,0.f,0.f,0.f};
  f32x4 acc[4][4];
  #pragma unroll
  for (int i=0;i<4;i++)
    #pragma unroll
    for (int j=0;j<4;j++) acc[i][j] = z4;

  for (int kt=0; kt<D_MODEL; kt+=64){
    #pragma unroll
    for (int i=0;i<4;i++)
      gll16(A  + (bm0+rS[i])*D_MODEL + kt + cS[i]*8, sA + (i*256 + w*64)*8);
    #pragma unroll
    for (int i=0;i<4;i++)
      gll16(Bt + (bn0+rS[i])*D_MODEL + kt + cS[i]*8, sB + (i*256 + w*64)*8);
    __syncthreads();
    #pragma unroll
    for (int kk=0; kk<2; ++kk){
      bf16x8 af[4], bfr[4];
      const int cq = (kk*4 + quad) ^ swl;
      #pragma unroll
      for (int i=0;i<4;i++) af[i]  = *(const bf16x8*)(sA + ((wm + (i<<4) + lr)*8 + cq)*8);
      #pragma unroll
      for (int j=0;j<4;j++) bfr[j] = *(const bf16x8*)(sB + ((wn + (j<<4) + lr)*8 + cq)*8);
      #pragma unroll
      for (int i=0;i<4;i++)
        #pragma unroll
        for (int j=0;j<4;j++)
          acc[i][j] = __builtin_amdgcn_mfma_f32_16x16x32_bf16(af[i], bfr[j], acc[i][j], 0, 0, 0);
    }
    __syncthreads();
  }

  const int z = bn0 >> 10;          // 0=Q, 1=K, 2=V
  const int ncl = bn0 & 1023;       // col base within region
  const int rq = quad<<2;

  if (z == 2){
    // transposed V: Vt[((b*NH+h)*HD+d)*T + t]
    #pragma unroll
    for (int i=0;i<4;i++){
      int row0 = bm0 + wm + (i<<4) + rq;
      int bb = row0 >> 11, tt = row0 & (T_SEQ-1);
      #pragma unroll
      for (int j=0;j<4;j++){
        int nv = ncl + wn + (j<<4) + lr;
        int hh = nv >> 6, dd = nv & 63;
        u16x4 st;
        #pragma unroll
        for (int r=0;r<4;r++) st[r] = f2b(acc[i][j][r]);
        *(u16x4*)(Vt + ((bb*NH + hh)*HD + dd)*T_SEQ + tt) = st;
      }
    }
  } else {
    const float* w_ = (z==0) ? qw : kw;
    u16* dst = (z==0) ? Qb : Kb;
    const float scale = (z==0) ? 0.125f : 1.0f;   // fold 1/sqrt(hd) into Q
    float wv[4];
    #pragma unroll
    for (int j=0;j<4;j++) wv[j] = w_[(j<<4) + lr];   // d = j*16+lr (one head per wave)
    #pragma unroll
    for (int i=0;i<4;i++){
      #pragma unroll
      for (int r=0;r<4;r++){
        const int grow = bm0 + wm + (i<<4) + rq + r;
        float ss = 0.f;
        #pragma unroll
        for (int j=0;j<4;j++) ss += acc[i][j][r]*acc[i][j][r];
        #pragma unroll
        for (int off=8; off>=1; off>>=1) ss += __shfl_xor(ss, off, 64);
        const float rms = rsqrtf(ss*(1.0f/64.0f) + 1e-6f);
        float xn[4];
        #pragma unroll
        for (int j=0;j<4;j++) xn[j] = acc[i][j][r]*rms*wv[j];
        const int t = grow & (T_SEQ-1);
        f32x2 c0 = *(const f32x2*)(cs + (t*32 + lr)*2);
        f32x2 c1 = *(const f32x2*)(cs + (t*32 + 16 + lr)*2);
        float o0 = xn[0]*c0[0] - xn[2]*c0[1];
        float o2 = xn[2]*c0[0] + xn[0]*c0[1];
        float o1 = xn[1]*c1[0] - xn[3]*c1[1];
        float o3 = xn[3]*c1[0] + xn[1]*c1[1];
        u16* rp = dst + grow*D_MODEL + ncl + wn + lr;
        rp[0]  = f2b(o0*scale);
        rp[16] = f2b(o1*scale);
        rp[32] = f2b(o2*scale);
        rp[48] = f2b(o3*scale);
      }
    }
  }
}

// ============== output GEMM, BK=64, f32 out ==============
// grid 256 1D; XCD k=id&7 owns bm in [k*4, k*4+4), all 8 bn.
__global__ __launch_bounds__(256) void gemm_out(
    const u16* __restrict__ A, const u16* __restrict__ Bt, float* __restrict__ out)
{
  __shared__ __align__(16) u16 sA[1024*8];
  __shared__ __align__(16) u16 sB[1024*8];
  const int id = blockIdx.x;
  const int xcd = id & 7, slot = id >> 3;    // slot 0..31
  const int bn = slot & 7;
  const int bm = xcd*4 + (slot>>3);
  const int bm0 = bm<<7, bn0 = bn<<7;

  const int tid = threadIdx.x;
  const int lane = tid & 63;
  const int w  = tid>>6;
  const int wm = (w>>1)<<6;
  const int wn = (w&1)<<6;
  const int quad = lane>>4, lr = lane&15;
  const int swl = lr & 7;

  int rS[4], cS[4];
  #pragma unroll
  for (int i=0;i<4;i++){
    int s = i*256 + tid;
    rS[i] = s>>3;
    cS[i] = (s&7) ^ (rS[i]&7);
  }

  const f32x4 z4 = {0.f,0.f,0.f,0.f};
  f32x4 acc[4][4];
  #pragma unroll
  for (int i=0;i<4;i++)
    #pragma unroll
    for (int j=0;j<4;j++) acc[i][j] = z4;

  for (int kt=0; kt<D_MODEL; kt+=64){
    #pragma unroll
    for (int i=0;i<4;i++)
      gll16(A  + (bm0+rS[i])*D_MODEL + kt + cS[i]*8, sA + (i*256 + w*64)*8);
    #pragma unroll
    for (int i=0;i<4;i++)
      gll16(Bt + (bn0+rS[i])*D_MODEL + kt + cS[i]*8, sB + (i*256 + w*64)*8);
    __syncthreads();
    #pragma unroll
    for (int kk=0; kk<2; ++kk){
      bf16x8 af[4], bfr[4];
      const int cq = (kk*4 + quad) ^ swl;
      #pragma unroll
      for (int i=0;i<4;i++) af[i]  = *(const bf16x8*)(sA + ((wm + (i<<4) + lr)*8 + cq)*8);
      #pragma unroll
      for (int j=0;j<4;j++) bfr[j] = *(const bf16x8*)(sB + ((wn + (j<<4) + lr)*8 + cq)*8);
      #pragma unroll
      for (int i=0;i<4;i++)
        #pragma unroll
        for (int j=0;j<4;j++)
          acc[i][j] = __builtin_amdgcn_mfma_f32_16x16x32_bf16(af[i], bfr[j], acc[i][j], 0, 0, 0);
    }
    __syncthreads();
  }

  const int rq = quad<<2;
  #pragma unroll
  for (int i=0;i<4;i++){
    #pragma unroll
    for (int r=0;r<4;r++){
      const int grow = bm0 + wm + (i<<4) + rq + r;
      #pragma unroll
      for (int j=0;j<4;j++)
        out[grow*D_MODEL + bn0 + wn + (j<<4) + lr] = acc[i][j][r];
    }
  }
}

// ---------------- MFMA flash attention, no-max softmax, dbuf gll staging ----------
// |q|2<=1, |k|2=8 after rmsnorm+scale => |s|<=8; p=exp(s-8)<=1. acc init = -8.
// K/VT tiles in swizzled slots: slot(row,c) = row*8 + (c^(row&7)), c = 16B chunk.
__global__ __launch_bounds__(256) void attn_mfma(const u16* __restrict__ Qb, const u16* __restrict__ Kb,
                                                 const u16* __restrict__ Vt, u16* __restrict__ AO)
{
  __shared__ __align__(16) u16 sK [2][512*8];   // 8KB each
  __shared__ __align__(16) u16 sVT[2][512*8];
  __shared__ __align__(16) u16 sP [4][16*68];
  const int tid = threadIdx.x;
  const int h  = blockIdx.x, b = blockIdx.y;
  const int qt = 31 - blockIdx.z;            // largest-first
  const int w = tid>>6, lane = tid&63;
  const int quad = lane>>4, lr = lane&15;
  const int q8 = quad<<3;

  const int s0 = w*64 + lane, s1 = 256 + w*64 + lane;
  const int r0s = s0>>3, c0s = (s0&7)^(r0s&7);
  const int r1s = s1>>3, c1s = (s1&7)^(r1s&7);
  const u16* Kbase = Kb + (b*T_SEQ)*D_MODEL + h*HD;
  const u16* Vbase = Vt + (b*NH + h)*HD*T_SEQ;
  const int ldsOff0 = (w*64)*8, ldsOff1 = (256 + w*64)*8;

  const u16* Qrow = Qb + (b*T_SEQ + qt*64 + w*16 + lr)*D_MODEL + h*HD;
  bf16x8 qf0 = *(const bf16x8*)(Qrow + q8);
  bf16x8 qf1 = *(const bf16x8*)(Qrow + 32 + q8);

  f32x4 o[4];
  float lp[4];
  const f32x4 z4 = {0.f,0.f,0.f,0.f};
  const f32x4 i8 = {-8.f,-8.f,-8.f,-8.f};
  #pragma unroll
  for (int r=0;r<4;r++) lp[r] = 0.f;
  #pragma unroll
  for (int nt=0;nt<4;nt++) o[nt] = z4;

  u16* myP = sP[w];

  gll16(Kbase + r0s*D_MODEL + c0s*8, &sK[0][ldsOff0]);
  gll16(Kbase + r1s*D_MODEL + c1s*8, &sK[0][ldsOff1]);
  gll16(Vbase + r0s*T_SEQ + c0s*8,   &sVT[0][ldsOff0]);
  gll16(Vbase + r1s*T_SEQ + c1s*8,   &sVT[0][ldsOff1]);
  __syncthreads();

  for (int kt=0; kt<=qt; ++kt){
    const int cur = kt&1;
    if (kt < qt){
      const int kn = kt+1, nb = cur^1;
      gll16(Kbase + (kn*64 + r0s)*D_MODEL + c0s*8, &sK[nb][ldsOff0]);
      gll16(Kbase + (kn*64 + r1s)*D_MODEL + c1s*8, &sK[nb][ldsOff1]);
      gll16(Vbase + r0s*T_SEQ + kn*64 + c0s*8,     &sVT[nb][ldsOff0]);
      gll16(Vbase + r1s*T_SEQ + kn*64 + c1s*8,     &sVT[nb][ldsOff1]);
    }

    f32x4 s4[4];
    #pragma unroll
    for (int ct=0; ct<4; ++ct){
      const int row = ct*16 + lr;
      const int sw = row&7;
      bf16x8 k0 = *(const bf16x8*)(&sK[cur][(row*8 + (quad     ^ sw))*8]);
      bf16x8 k1 = *(const bf16x8*)(&sK[cur][(row*8 + ((4+quad) ^ sw))*8]);
      f32x4 acc = i8;
      acc = __builtin_amdgcn_mfma_f32_16x16x32_bf16(qf0, k0, acc, 0,0,0);
      acc = __builtin_amdgcn_mfma_f32_16x16x32_bf16(qf1, k1, acc, 0,0,0);
      s4[ct] = acc;
    }

    if (kt == qt){
      #pragma unroll
      for (int ct=0; ct<4; ++ct){
        int col = ct*16 + lr;
        #pragma unroll
        for (int r=0;r<4;r++)
          if (col > w*16 + quad*4 + r) s4[ct][r] = -1e30f;
      }
    }

    #pragma unroll
    for (int ct=0; ct<4; ++ct){
      #pragma unroll
      for (int r=0;r<4;r++){
        float p = __expf(s4[ct][r]);
        u32 pu = __float_as_uint(p) & 0xffff0000u;
        lp[r] += __uint_as_float(pu);
        myP[(quad*4 + r)*68 + ct*16 + lr] = (u16)(pu>>16);
      }
    }

    #pragma unroll
    for (int st=0; st<2; ++st){
      bf16x8 pf = *(const bf16x8*)(myP + lr*68 + st*32 + q8);
      #pragma unroll
      for (int nt=0;nt<4;nt++){
        const int row = nt*16 + lr;
        const int slot = row*8 + ((st*4+quad) ^ (row&7));
        bf16x8 vf = *(const bf16x8*)(&sVT[cur][slot*8]);
        o[nt] = __builtin_amdgcn_mfma_f32_16x16x32_bf16(pf, vf, o[nt], 0,0,0);
      }
    }
    __syncthreads();
  }

  #pragma unroll
  for (int r=0;r<4;r++){
    #pragma unroll
    for (int off=8; off>=1; off>>=1) lp[r] += __shfl_xor(lp[r], off, 64);
  }
  const int rowg = b*T_SEQ + qt*64 + w*16 + quad*4;
  #pragma unroll
  for (int r=0;r<4;r++){
    float inv = 1.0f / lp[r];
    #pragma unroll
    for (int nt=0;nt<4;nt++)
      AO[(rowg + r)*D_MODEL + h*HD + nt*16 + lr] = f2b(o[nt][r]*inv);
  }
}

extern "C" void kernel_launch(void* const* d_in, const int* in_sizes, int n_in,
                              void* d_out, int out_size, void* d_ws, size_t ws_size,
                              hipStream_t stream)
{
  const float* X  = (const float*)d_in[0];
  const float* Wq = (const float*)d_in[1];
  const float* Wk = (const float*)d_in[2];
  const float* Wv = (const float*)d_in[3];
  const float* Wo = (const float*)d_in[4];
  const float* qw = (const float*)d_in[5];
  const float* kw = (const float*)d_in[6];

  char* ws = (char*)d_ws;
  const size_t MB = 1024*1024;
  u16*   WqkvT = (u16*)(ws + 0*MB);        // 6 MB (WqT|WkT|WvT)
  u16*   WoT   = (u16*)(ws + 6*MB);        // 2 MB
  u16*   Xb    = (u16*)(ws + 8*MB);        // 8 MB
  u16*   Qb    = (u16*)(ws + 16*MB);       // 8 MB
  u16*   Kb    = (u16*)(ws + 24*MB);       // 8 MB
  u16*   Vt    = (u16*)(ws + 32*MB);       // 8 MB
  u16*   AO    = (u16*)(ws + 40*MB);       // 8 MB
  float* CS    = (float*)(ws + 48*MB);     // 512 KB rope table

  f32_to_bf16<<<dim3(4096), 256, 0, stream>>>(X, Xb);
  transpose_w<<<dim3(32,32,4), dim3(32,8), 0, stream>>>(
      Wq,Wk,Wv,Wo, WqkvT, WqkvT + 1024*1024, WqkvT + 2*1024*1024, WoT);
  rope_table<<<dim3(256), 256, 0, stream>>>(CS);
  gemm_qkv<<<dim3(768), 256, 0, stream>>>(Xb, WqkvT, qw, kw, CS, Qb, Kb, Vt);
  attn_mfma<<<dim3(NH, 2, 32), 256, 0, stream>>>(Qb, Kb, Vt, AO);
  gemm_out<<<dim3(256), 256, 0, stream>>>(AO, WoT, (float*)d_out);
}